// Round 7
// baseline (400.655 us; speedup 1.0000x reference)
//
#include <hip/hip_runtime.h>
#include <hip/hip_cooperative_groups.h>

namespace cg = cooperative_groups;

// Problem constants (setup_inputs is fixed)
#define BATCH 2
#define NTXT  2048
#define TMED  4
#define MMED  256
#define TM    (TMED * MMED)      // 1024 kv rows per batch
#define DIM   1024
#define NH    16
#define DHD   64
#define KVW   2048               // k|v concatenated width
#define RMAX  256                // max real rows per batch via qpart fast path
#define QSTR  ((size_t)BATCH * RMAX * DIM)   // stride between qpart chunks
#define NB    256                // cooperative grid: one block per CU
#define NT    512                // threads per block (8 waves)

typedef _Float16 f16x8 __attribute__((ext_vector_type(8)));
typedef float    f32x4 __attribute__((ext_vector_type(4)));

// ---------------------------------------------------------------------------
// Per-row attention (all 16 heads) + output projection, 512 threads.
// rq >= 0: q comes from qpart[rq]. rq < 0: compute LN + q directly (rare
// fallback for rows beyond RMAX; unreachable for realistic inputs).
// ---------------------------------------------------------------------------
__device__ void attn_row(char* SMEM, int b, int i, int rq,
                         const float* __restrict__ text,
                         const float* __restrict__ Wq,
                         const float* __restrict__ Wo,
                         const float* __restrict__ gamma,
                         const float* __restrict__ beta,
                         const _Float16* __restrict__ kv16,
                         const float* __restrict__ qpart,
                         const int* __restrict__ tt,
                         float* __restrict__ out) {
  float* qrow  = (float*)SMEM;         // 1024
  float* oaccs = qrow + 1024;          // 1024
  float* tns   = oaccs + 1024;         // 1024
  float* red   = tns + 1024;           // 512
  float* pbuf  = red + 512;            // 512   (total 16 KB)
  const int tid = threadIdx.x;
  const int t = tt[b * NTXT + i];      // in [1, TMED]

  if (rq >= 0) {
    for (int c = tid; c < DIM; c += NT) {
      const size_t qoff = (size_t)(b * RMAX + rq) * DIM + c;
      qrow[c] = qpart[qoff] + qpart[QSTR + qoff] +
                qpart[2 * QSTR + qoff] + qpart[3 * QSTR + qoff];
    }
  } else {
    // LayerNorm + direct q matvec
    const float* xrow = text + (size_t)(b * NTXT + i) * DIM;
    const float x0 = xrow[tid], x1 = xrow[tid + 512];
    red[tid] = x0 + x1; __syncthreads();
    for (int st = 256; st > 0; st >>= 1) {
      if (tid < st) red[tid] += red[tid + st];
      __syncthreads();
    }
    const float mu = red[0] * (1.0f / DIM); __syncthreads();
    const float d0 = x0 - mu, d1 = x1 - mu;
    red[tid] = d0 * d0 + d1 * d1; __syncthreads();
    for (int st = 256; st > 0; st >>= 1) {
      if (tid < st) red[tid] += red[tid + st];
      __syncthreads();
    }
    const float rstd = rsqrtf(red[0] * (1.0f / DIM) + 1e-5f); __syncthreads();
    tns[tid]       = d0 * rstd * gamma[tid] + beta[tid];
    tns[tid + 512] = d1 * rstd * gamma[tid + 512] + beta[tid + 512];
    __syncthreads();
    for (int n = tid; n < DIM; n += NT) {
      float a = 0.f;
      for (int c = 0; c < DIM; c++) a += tns[c] * Wq[(size_t)c * DIM + n];
      qrow[n] = a;
    }
  }
  __syncthreads();

  const size_t kvrow0 = (size_t)(b * TM + (t - 1) * MMED) * KVW;
  // 8 head-pairs: lanes split (head-half hh = tid>>8, kv col j = tid&255)
  for (int hp = 0; hp < 8; hp++) {
    const int hh = tid >> 8;
    const int h = hp * 2 + hh;
    const int j = tid & 255;
    const _Float16* krow = kv16 + kvrow0 + (size_t)j * KVW + h * DHD;
    float sc = 0.f;
#pragma unroll
    for (int d = 0; d < DHD; d += 8) {
      const f16x8 kk = *reinterpret_cast<const f16x8*>(krow + d);
#pragma unroll
      for (int u = 0; u < 8; u++) sc += qrow[h * DHD + d + u] * (float)kk[u];
    }
    sc *= 0.125f;
    red[tid] = sc; __syncthreads();
    for (int st = 128; st > 0; st >>= 1) {
      if ((tid & 255) < st) red[tid] = fmaxf(red[tid], red[tid + st]);
      __syncthreads();
    }
    const float mx = red[tid & 256]; __syncthreads();
    const float e = __expf(sc - mx);
    red[tid] = e; __syncthreads();
    for (int st = 128; st > 0; st >>= 1) {
      if ((tid & 255) < st) red[tid] += red[tid + st];
      __syncthreads();
    }
    const float inv = 1.0f / red[tid & 256]; __syncthreads();
    pbuf[tid] = e * inv; __syncthreads();
    // PV: tid = q4*128 + hh2*64 + d0
    const int q4 = tid >> 7, hh2 = (tid >> 6) & 1, dd = tid & 63;
    const int h2 = hp * 2 + hh2;
    const _Float16* vb =
        kv16 + kvrow0 + (size_t)(q4 * 64) * KVW + DIM + h2 * DHD + dd;
    float a = 0.f;
#pragma unroll 8
    for (int jj = 0; jj < 64; jj++)
      a += pbuf[hh2 * 256 + q4 * 64 + jj] * (float)vb[(size_t)jj * KVW];
    red[tid] = a; __syncthreads();
    if (tid < 128)
      oaccs[hp * 128 + tid] =
          red[tid] + red[128 + tid] + red[256 + tid] + red[384 + tid];
    __syncthreads();
  }
  // output projection
  float* orow = out + (size_t)(b * NTXT + i) * DIM;
  for (int e = tid; e < DIM; e += NT) {
    float s = 0.f;
    for (int c = 0; c < DIM; c++) s += oaccs[c] * Wo[(size_t)c * DIM + e];
    orow[e] = s;
  }
  __syncthreads();
}

// ---------------------------------------------------------------------------
// The single cooperative kernel. 256 blocks x 512 threads, grid.sync phases.
// ---------------------------------------------------------------------------
__global__ __launch_bounds__(NT) void mega_kernel(
    const int* __restrict__ loc, const float* __restrict__ image,
    const float* __restrict__ text, const float* __restrict__ Wkv,
    const float* __restrict__ Wq, const float* __restrict__ Wo,
    const float* __restrict__ gamma, const float* __restrict__ beta,
    float* __restrict__ out, _Float16* __restrict__ WkvT,
    _Float16* __restrict__ kv16, float* __restrict__ tn,
    float* __restrict__ qpart, float* __restrict__ ibar,
    float* __restrict__ vbar, float* __restrict__ obar,
    int* __restrict__ tt, int* __restrict__ seg) {
  cg::grid_group grid = cg::this_grid();
  __shared__ char SMEM[16640];
  __shared__ int s_start, s_end;
  const int bid = blockIdx.x;
  const int tid = threadIdx.x;

  // ========== P0: scan (blocks 0,1) | zero (block 2) | WkvT transpose ======
  if (bid < BATCH) {
    const int b = bid;
    int* tots = (int*)SMEM;                       // 512 ints
    if (tid == 0) { s_start = NTXT; s_end = NTXT; }
    int v[4];
    int run = 0;
    const int base = b * NTXT + tid * 4;
#pragma unroll
    for (int k = 0; k < 4; k++) { run += loc[base + k]; v[k] = run; }
    tots[tid] = run; __syncthreads();
    for (int off = 1; off < 512; off <<= 1) {
      const int add = (tid >= off) ? tots[tid - off] : 0;
      __syncthreads();
      tots[tid] += add;
      __syncthreads();
    }
    const int excl = tots[tid] - run;
#pragma unroll
    for (int k = 0; k < 4; k++) {
      const int tv = excl + v[k];
      tt[base + k] = tv;
      if (tv >= 1) atomicMin(&s_start, tid * 4 + k);
      if (tv >= 5) atomicMin(&s_end, tid * 4 + k);
    }
    __syncthreads();
    if (tid == 0) {
      seg[b * 2]     = s_start;
      seg[b * 2 + 1] = s_end - s_start;
    }
  } else if (bid == 2) {
    // zero ibar | vbar | obar (contiguous, 6144 floats)
    for (int c = tid; c < 3 * BATCH * DIM; c += NT) ibar[c] = 0.f;
  }
  // Wkv transpose: 512 tiles of 64x64, 2 per block
  {
    float (*tile)[65] = (float(*)[65])SMEM;
    for (int tile_id = bid * 2; tile_id < bid * 2 + 2; tile_id++) {
      const int k0 = (tile_id & 15) * 64, n0 = (tile_id >> 4) * 64;
      __syncthreads();
      const int r = tid >> 3, c8 = (tid & 7) * 8;
      const float4 v0 = *reinterpret_cast<const float4*>(
          Wkv + (size_t)(k0 + r) * KVW + n0 + c8);
      const float4 v1 = *reinterpret_cast<const float4*>(
          Wkv + (size_t)(k0 + r) * KVW + n0 + c8 + 4);
      tile[r][c8 + 0] = v0.x; tile[r][c8 + 1] = v0.y;
      tile[r][c8 + 2] = v0.z; tile[r][c8 + 3] = v0.w;
      tile[r][c8 + 4] = v1.x; tile[r][c8 + 5] = v1.y;
      tile[r][c8 + 6] = v1.z; tile[r][c8 + 7] = v1.w;
      __syncthreads();
      const int n = tid >> 3, kc = (tid & 7) * 8;
      f16x8 h;
#pragma unroll
      for (int j = 0; j < 8; j++) h[j] = (_Float16)tile[kc + j][n];
      *reinterpret_cast<f16x8*>(WkvT + (size_t)(n0 + n) * DIM + k0 + kc) = h;
    }
  }
  grid.sync();

  // ========== P1: ibar (blocks 0..127) | LN (blocks 128..191) ==============
  if (bid < 128) {
    const int b = bid >> 6, rt2 = bid & 63;       // 64 tiles of 16 rows
    const float* p = image + (size_t)(b * TM + rt2 * 16) * DIM + tid;
#pragma unroll
    for (int half = 0; half < 2; half++) {
      float s = 0.f;
#pragma unroll
      for (int r = 0; r < 16; r++) s += p[(size_t)r * DIM + half * 512];
      atomicAdd(&ibar[b * DIM + tid + half * 512], s * (1.0f / (float)TM));
    }
  } else if (bid < 192) {
    const int sidx = bid - 128;
    const int b = sidx >> 5, rt = sidx & 31;
    const int i0 = seg[b * 2];
    const int cnt = min(seg[b * 2 + 1], RMAX);
    float* red = (float*)SMEM;
    for (int r = rt; r < cnt; r += 32) {
      const float* xrow = text + (size_t)(b * NTXT + i0 + r) * DIM;
      const float x0 = xrow[tid], x1 = xrow[tid + 512];
      red[tid] = x0 + x1; __syncthreads();
      for (int st = 256; st > 0; st >>= 1) {
        if (tid < st) red[tid] += red[tid + st];
        __syncthreads();
      }
      const float mu = red[0] * (1.0f / DIM); __syncthreads();
      const float d0 = x0 - mu, d1 = x1 - mu;
      red[tid] = d0 * d0 + d1 * d1; __syncthreads();
      for (int st = 256; st > 0; st >>= 1) {
        if (tid < st) red[tid] += red[tid + st];
        __syncthreads();
      }
      const float rstd = rsqrtf(red[0] * (1.0f / DIM) + 1e-5f); __syncthreads();
      float* trow = tn + (size_t)(b * RMAX + r) * DIM;
      trow[tid]       = d0 * rstd * gamma[tid] + beta[tid];
      trow[tid + 512] = d1 * rstd * gamma[tid + 512] + beta[tid + 512];
      __syncthreads();
    }
  }
  grid.sync();

  // ========== P2: GEMM (all blocks) then qproj (0..63) / vbar (64..95) =====
  {
    _Float16* As = (_Float16*)SMEM;               // 128*32 f16 = 8 KB
    _Float16* Bs = As + 128 * 32;                 // 8 KB
    const int lane = tid & 63, wid = tid >> 6;
    const int wm = wid & 3, wn = wid >> 2;
    const int row0 = (bid >> 4) * 128, col0 = (bid & 15) * 128;
    const int srow = tid >> 2, skc = (tid & 3) * 8;
    const int frow = lane & 15, fq = lane >> 4;
    f32x4 acc[2][4] = {};
    for (int k0 = 0; k0 < DIM; k0 += 32) {
      const float* ap = image + (size_t)(row0 + srow) * DIM + k0 + skc;
      const float4 a0 = *reinterpret_cast<const float4*>(ap);
      const float4 a1 = *reinterpret_cast<const float4*>(ap + 4);
      f16x8 av;
      av[0] = (_Float16)a0.x; av[1] = (_Float16)a0.y;
      av[2] = (_Float16)a0.z; av[3] = (_Float16)a0.w;
      av[4] = (_Float16)a1.x; av[5] = (_Float16)a1.y;
      av[6] = (_Float16)a1.z; av[7] = (_Float16)a1.w;
      const f16x8 bv = *reinterpret_cast<const f16x8*>(
          WkvT + (size_t)(col0 + srow) * DIM + k0 + skc);
      __syncthreads();
      *reinterpret_cast<f16x8*>(As + tid * 8) = av;
      *reinterpret_cast<f16x8*>(Bs + tid * 8) = bv;
      __syncthreads();
      f16x8 af[2], bf[4];
#pragma unroll
      for (int mt = 0; mt < 2; mt++)
        af[mt] = *reinterpret_cast<const f16x8*>(
            As + (wm * 32 + mt * 16 + frow) * 32 + fq * 8);
#pragma unroll
      for (int nt = 0; nt < 4; nt++)
        bf[nt] = *reinterpret_cast<const f16x8*>(
            Bs + (wn * 64 + nt * 16 + frow) * 32 + fq * 8);
#pragma unroll
      for (int mt = 0; mt < 2; mt++)
#pragma unroll
        for (int nt = 0; nt < 4; nt++)
          acc[mt][nt] = __builtin_amdgcn_mfma_f32_16x16x32_f16(
              af[mt], bf[nt], acc[mt][nt], 0, 0, 0);
    }
#pragma unroll
    for (int mt = 0; mt < 2; mt++)
#pragma unroll
      for (int nt = 0; nt < 4; nt++) {
        const int col = col0 + wn * 64 + nt * 16 + frow;
#pragma unroll
        for (int r = 0; r < 4; r++) {
          const int row = row0 + wm * 32 + mt * 16 + fq * 4 + r;
          kv16[(size_t)row * KVW + col] = (_Float16)acc[mt][nt][r];
        }
      }
    __syncthreads();
  }
  if (bid < 64) {
    // qproj: qpart[cc][r, n0+n] = tn[r, c0:c0+256] @ Wq[c0:c0+256, n0+n]
    float* tn_s = (float*)SMEM;                   // 8 x 256 f32 = 8 KB
    const int b = bid >> 5, nt = (bid >> 2) & 7, cc = bid & 3;
    const int n0 = nt * 128, c0 = cc * 256;
    const int n = tid & 127, rp = tid >> 7;       // 4 row-pairs
    const int cnt = min(seg[b * 2 + 1], RMAX);
    float* qp = qpart + (size_t)cc * QSTR;
    for (int r0 = 0; r0 < cnt; r0 += 8) {
      const int rows = min(8, cnt - r0);
      for (int i2 = tid; i2 < 8 * 256; i2 += NT) {
        const int r = i2 >> 8, c = i2 & 255;
        tn_s[i2] = (r < rows)
                       ? tn[(size_t)(b * RMAX + r0 + r) * DIM + c0 + c] : 0.f;
      }
      __syncthreads();
      float a0 = 0.f, a1 = 0.f;
      for (int c = 0; c < 256; c++) {
        const float w = Wq[(size_t)(c0 + c) * DIM + n0 + n];
        a0 += tn_s[(rp * 2) * 256 + c] * w;
        a1 += tn_s[(rp * 2 + 1) * 256 + c] * w;
      }
      if (rp * 2 < rows)
        qp[(size_t)(b * RMAX + r0 + rp * 2) * DIM + n0 + n] = a0;
      if (rp * 2 + 1 < rows)
        qp[(size_t)(b * RMAX + r0 + rp * 2 + 1) * DIM + n0 + n] = a1;
      __syncthreads();
    }
  } else if (bid < 96) {
    // vbar: vbar[b,e] += ibar[b,c0:c0+128] @ Wkv[c0:c0+128, DIM+e]
    float* vb_s = (float*)SMEM;
    const int sidx = bid - 64;
    const int b = sidx >> 4, et = (sidx >> 3) & 1, cc = sidx & 7;
    const int e = et * 512 + tid, c0 = cc * 128;
    if (tid < 128) vb_s[tid] = ibar[b * DIM + c0 + tid];
    __syncthreads();
    float s = 0.f;
    for (int c = 0; c < 128; c++)
      s += vb_s[c] * Wkv[(size_t)(c0 + c) * KVW + DIM + e];
    atomicAdd(&vbar[b * DIM + e], s);
  }
  grid.sync();

  // ========== P3: obar (blocks 0..31) ======================================
  if (bid < 32) {
    float* vb_s = (float*)SMEM;
    const int b = bid >> 4, et = (bid >> 3) & 1, cc = bid & 7;
    const int e = et * 512 + tid, c0 = cc * 128;
    if (tid < 128) vb_s[tid] = vbar[b * DIM + c0 + tid];
    __syncthreads();
    float s = 0.f;
    for (int c = 0; c < 128; c++)
      s += vb_s[c] * Wo[(size_t)(c0 + c) * DIM + e];
    atomicAdd(&obar[b * DIM + e], s);
  }
  grid.sync();

  // ========== P4: fill (grid-stride) + per-row attention ====================
  const int cnt0 = min(seg[1], RMAX), cnt1 = min(seg[3], RMAX);
  for (int row = bid; row < BATCH * NTXT; row += NB) {
    const int b = row >> 11, i = row & (NTXT - 1);
    const int t = tt[row];
    float* orow = out + (size_t)row * DIM;
    if (t == 0) {
      orow[tid] = 0.f; orow[tid + 512] = 0.f;
    } else if (t > TMED) {
      orow[tid] = obar[b * DIM + tid];
      orow[tid + 512] = obar[b * DIM + tid + 512];
    } else if (i - seg[b * 2] >= RMAX) {
      // rare fallback: direct LN + q + attention + oproj
      attn_row(SMEM, b, i, -1, text, Wq, Wo, gamma, beta, kv16, qpart, tt, out);
    }
  }
  for (int s = bid; s < cnt0 + cnt1; s += NB) {
    const int b = (s < cnt0) ? 0 : 1;
    const int r = (s < cnt0) ? s : s - cnt0;
    attn_row(SMEM, b, seg[b * 2] + r, r, text, Wq, Wo, gamma, beta, kv16,
             qpart, tt, out);
  }
}

// ---------------------------------------------------------------------------
extern "C" void kernel_launch(void* const* d_in, const int* in_sizes, int n_in,
                              void* d_out, int out_size, void* d_ws, size_t ws_size,
                              hipStream_t stream) {
  const float* text  = (const float*)d_in[0];
  const float* image = (const float*)d_in[1];
  const int*   loc   = (const int*)d_in[2];
  const float* Wq    = (const float*)d_in[3];
  const float* Wkv   = (const float*)d_in[4];
  const float* Wo    = (const float*)d_in[5];
  const float* gamma = (const float*)d_in[6];
  const float* beta  = (const float*)d_in[7];
  float* out = (float*)d_out;

  // ws layout: kv16 8MB | WkvT 4MB | tn 2MB | qpart 4x2MB | ibar|vbar|obar |
  //            tt | seg   (~23 MB)
  _Float16* kv16  = (_Float16*)d_ws;
  _Float16* WkvT  = kv16 + (size_t)BATCH * TM * KVW;
  float*    tn    = (float*)(WkvT + (size_t)KVW * DIM);
  float*    qpart = tn + (size_t)BATCH * RMAX * DIM;
  float*    ibar  = qpart + 4 * QSTR;
  float*    vbar  = ibar + BATCH * DIM;
  float*    obar  = vbar + BATCH * DIM;
  int*      tt    = (int*)(obar + BATCH * DIM);
  int*      seg   = tt + BATCH * NTXT;

  void* args[] = {(void*)&loc,  (void*)&image, (void*)&text, (void*)&Wkv,
                  (void*)&Wq,   (void*)&Wo,    (void*)&gamma, (void*)&beta,
                  (void*)&out,  (void*)&WkvT,  (void*)&kv16, (void*)&tn,
                  (void*)&qpart,(void*)&ibar,  (void*)&vbar, (void*)&obar,
                  (void*)&tt,   (void*)&seg};
  hipLaunchCooperativeKernel((void*)mega_kernel, dim3(NB), dim3(NT), args, 0,
                             stream);
}

// Round 8
// 182.373 us; speedup vs baseline: 2.1969x; 2.1969x over previous
//
#include <hip/hip_runtime.h>

// Problem constants (setup_inputs is fixed)
#define BATCH 2
#define NTXT  2048
#define TMED  4
#define MMED  256
#define TM    (TMED * MMED)      // 1024 kv rows per batch
#define DIM   1024
#define NH    16
#define DHD   64
#define KVW   2048               // k|v concatenated width
#define RMAX  256                // max real rows per batch via qpart fast path
#define QSTR  ((size_t)BATCH * RMAX * DIM)   // stride between qpart chunks

typedef _Float16 f16x8 __attribute__((ext_vector_type(8)));
typedef float    f32x4 __attribute__((ext_vector_type(4)));

// ---------------------------------------------------------------------------
// K1: blocks 0..1   : inclusive scan of locations -> txt_time + segment
//     block  2      : zero vbar|obar (contiguous 4096 floats)
//     blocks 3..514 : Wkv (K x N f32) -> WkvT (N x K f16) transpose
// ---------------------------------------------------------------------------
__global__ __launch_bounds__(256) void k1_prep(
    const int* __restrict__ loc, const float* __restrict__ Wkv,
    int* __restrict__ tt, int* __restrict__ seg, float* __restrict__ vbar,
    _Float16* __restrict__ WkvT) {
  __shared__ float tile[64][65];
  __shared__ int tots[256];
  __shared__ int s_start, s_end;
  const int bid = blockIdx.x;
  const int tid = threadIdx.x;
  if (bid < BATCH) {
    const int b = bid;
    if (tid == 0) { s_start = NTXT; s_end = NTXT; }
    __syncthreads();
    int v[8];
    int run = 0;
    const int base = b * NTXT + tid * 8;
#pragma unroll
    for (int k = 0; k < 8; k++) { run += loc[base + k]; v[k] = run; }
    tots[tid] = run; __syncthreads();
    for (int off = 1; off < 256; off <<= 1) {
      const int add = (tid >= off) ? tots[tid - off] : 0;
      __syncthreads();
      tots[tid] += add;
      __syncthreads();
    }
    const int excl = tots[tid] - run;
#pragma unroll
    for (int k = 0; k < 8; k++) {
      const int tv = excl + v[k];
      tt[base + k] = tv;
      if (tv >= 1) atomicMin(&s_start, tid * 8 + k);
      if (tv >= 5) atomicMin(&s_end, tid * 8 + k);
    }
    __syncthreads();
    if (tid == 0) {
      seg[b * 2]     = s_start;
      seg[b * 2 + 1] = s_end - s_start;
    }
  } else if (bid == 2) {
    for (int c = tid; c < 2 * BATCH * DIM; c += 256) vbar[c] = 0.f;
  } else {
    // ---- transpose+convert Wkv ----
    const int idx = bid - 3;                     // 0..511
    const int k0 = (idx & 15) * 64, n0 = (idx >> 4) * 64;
    const int r = tid >> 4, c4 = (tid & 15) * 4;
#pragma unroll
    for (int i = 0; i < 4; i++) {
      const float4 v = *reinterpret_cast<const float4*>(
          Wkv + (size_t)(k0 + r + i * 16) * KVW + n0 + c4);
      tile[r + i * 16][c4 + 0] = v.x; tile[r + i * 16][c4 + 1] = v.y;
      tile[r + i * 16][c4 + 2] = v.z; tile[r + i * 16][c4 + 3] = v.w;
    }
    __syncthreads();
#pragma unroll
    for (int it = 0; it < 2; it++) {
      const int chunk = it * 256 + tid;
      const int n = chunk >> 3, kc = (chunk & 7) * 8;
      f16x8 h;
#pragma unroll
      for (int j = 0; j < 8; j++) h[j] = (_Float16)tile[kc + j][n];
      *reinterpret_cast<f16x8*>(WkvT + (size_t)(n0 + n) * DIM + k0 + kc) = h;
    }
  }
}

// ---------------------------------------------------------------------------
// K2: blocks 0..255  : f16 MFMA GEMM kv16 = (f16)image @ WkvT^T (128x128)
//                      + vbar epilogue (fp32 column sums of v-half, atomics)
//     blocks 256..319: qproj with inline LayerNorm -> qpart[cc] (no atomics)
// ---------------------------------------------------------------------------
__global__ __launch_bounds__(512) void k2_gemm_qproj(
    const float* __restrict__ image, const _Float16* __restrict__ WkvT,
    const float* __restrict__ text, const float* __restrict__ Wq,
    const float* __restrict__ gamma, const float* __restrict__ beta,
    const int* __restrict__ seg, _Float16* __restrict__ kv16,
    float* __restrict__ qpart, float* __restrict__ vbar) {
  __shared__ char smem[16384];
  const int idx = blockIdx.x;
  const int tid = threadIdx.x;
  if (idx < 256) {
    // ---- GEMM (A staged f32->f16 in-register) ----
    _Float16* As = (_Float16*)smem;          // 128*32 f16 = 8 KB
    _Float16* Bs = As + 128 * 32;            // 8 KB
    const int lane = tid & 63, wid = tid >> 6;
    const int wm = wid & 3, wn = wid >> 2;
    const int row0 = (idx >> 4) * 128, col0 = (idx & 15) * 128;
    const int srow = tid >> 2, skc = (tid & 3) * 8;
    const int frow = lane & 15, fq = lane >> 4;
    f32x4 acc[2][4] = {};
    for (int k0 = 0; k0 < DIM; k0 += 32) {
      const float* ap = image + (size_t)(row0 + srow) * DIM + k0 + skc;
      const float4 a0 = *reinterpret_cast<const float4*>(ap);
      const float4 a1 = *reinterpret_cast<const float4*>(ap + 4);
      f16x8 av;
      av[0] = (_Float16)a0.x; av[1] = (_Float16)a0.y;
      av[2] = (_Float16)a0.z; av[3] = (_Float16)a0.w;
      av[4] = (_Float16)a1.x; av[5] = (_Float16)a1.y;
      av[6] = (_Float16)a1.z; av[7] = (_Float16)a1.w;
      const f16x8 bv = *reinterpret_cast<const f16x8*>(
          WkvT + (size_t)(col0 + srow) * DIM + k0 + skc);
      __syncthreads();
      *reinterpret_cast<f16x8*>(As + tid * 8) = av;
      *reinterpret_cast<f16x8*>(Bs + tid * 8) = bv;
      __syncthreads();
      f16x8 af[2], bf[4];
#pragma unroll
      for (int mt = 0; mt < 2; mt++)
        af[mt] = *reinterpret_cast<const f16x8*>(
            As + (wm * 32 + mt * 16 + frow) * 32 + fq * 8);
#pragma unroll
      for (int nt = 0; nt < 4; nt++)
        bf[nt] = *reinterpret_cast<const f16x8*>(
            Bs + (wn * 64 + nt * 16 + frow) * 32 + fq * 8);
#pragma unroll
      for (int mt = 0; mt < 2; mt++)
#pragma unroll
        for (int nt = 0; nt < 4; nt++)
          acc[mt][nt] = __builtin_amdgcn_mfma_f32_16x16x32_f16(
              af[mt], bf[nt], acc[mt][nt], 0, 0, 0);
    }
#pragma unroll
    for (int mt = 0; mt < 2; mt++)
#pragma unroll
      for (int nt = 0; nt < 4; nt++) {
        const int col = col0 + wn * 64 + nt * 16 + frow;
#pragma unroll
        for (int r = 0; r < 4; r++) {
          const int row = row0 + wm * 32 + mt * 16 + fq * 4 + r;
          kv16[(size_t)row * KVW + col] = (_Float16)acc[mt][nt][r];
        }
      }
    // ---- vbar epilogue: column sums of v-half, shuffle-reduced, atomics ----
    if (col0 >= DIM) {
      const int b = row0 >> 10;
#pragma unroll
      for (int nt = 0; nt < 4; nt++) {
        float s = 0.f;
#pragma unroll
        for (int mt = 0; mt < 2; mt++)
#pragma unroll
          for (int r = 0; r < 4; r++) s += acc[mt][nt][r];
        s += __shfl_down(s, 32);
        s += __shfl_down(s, 16);
        if (lane < 16)
          atomicAdd(&vbar[b * DIM + (col0 - DIM) + wn * 64 + nt * 16 + lane],
                    s * (1.0f / (float)TM));
      }
    }
  } else {
    // ---- qproj with inline LN: one wave per row for stats ----
    float* tn_s = (float*)smem;              // 8 x 256 f32 = 8 KB
    const int j = idx - 256;                 // 0..63
    const int b = j >> 5, nt = (j >> 2) & 7, cc = j & 3;
    const int n0 = nt * 128, c0 = cc * 256;
    const int lane = tid & 63, w = tid >> 6; // wave w handles row r0+w
    const int n = tid & 127, rp = tid >> 7;  // compute: 4 row-pairs
    const int i0 = seg[b * 2];
    const int cnt = min(seg[b * 2 + 1], RMAX);
    float* qp = qpart + (size_t)cc * QSTR;
    for (int r0 = 0; r0 < cnt; r0 += 8) {
      const int rows = min(8, cnt - r0);
      if (w < rows) {
        const float* xrow = text + (size_t)(b * NTXT + i0 + r0 + w) * DIM;
        float s = 0.f, sq = 0.f;
#pragma unroll
        for (int u = 0; u < 16; u++) {
          const float x = xrow[lane + 64 * u];
          s += x; sq += x * x;
        }
#pragma unroll
        for (int off = 32; off > 0; off >>= 1) {
          s += __shfl_xor(s, off);
          sq += __shfl_xor(sq, off);
        }
        const float mu = s * (1.0f / DIM);
        const float rstd = rsqrtf(sq * (1.0f / DIM) - mu * mu + 1e-5f);
#pragma unroll
        for (int u = 0; u < 4; u++) {
          const int c = c0 + lane + 64 * u;
          tn_s[w * 256 + lane + 64 * u] =
              (xrow[c] - mu) * rstd * gamma[c] + beta[c];
        }
      }
      __syncthreads();
      float a0 = 0.f, a1 = 0.f;
      for (int c = 0; c < 256; c++) {
        const float wv = Wq[(size_t)(c0 + c) * DIM + n0 + n];
        a0 += tn_s[(rp * 2) * 256 + c] * wv;
        a1 += tn_s[(rp * 2 + 1) * 256 + c] * wv;
      }
      if (rp * 2 < rows)
        qp[(size_t)(b * RMAX + r0 + rp * 2) * DIM + n0 + n] = a0;
      if (rp * 2 + 1 < rows)
        qp[(size_t)(b * RMAX + r0 + rp * 2 + 1) * DIM + n0 + n] = a1;
      __syncthreads();
    }
  }
}

// ---------------------------------------------------------------------------
// K3: blocks 0..31 : obar[b,e] += vbar[b,c0:c0+128] @ Wo[c0:c0+128,e] (atomics)
//     blocks 32..33: zero out rows of the real segment (for k4's atomics)
// ---------------------------------------------------------------------------
__global__ __launch_bounds__(512) void k3_obar_zero(
    const float* __restrict__ vbar, const float* __restrict__ Wo,
    const int* __restrict__ seg, float* __restrict__ obar,
    float* __restrict__ out) {
  __shared__ float vb_s[128];
  const int bid = blockIdx.x;
  const int tid = threadIdx.x;
  if (bid < 32) {
    const int b = bid >> 4, et = (bid >> 3) & 1, cc = bid & 7;
    const int e = et * 512 + tid, c0 = cc * 128;
    if (tid < 128) vb_s[tid] = vbar[b * DIM + c0 + tid];
    __syncthreads();
    float s = 0.f;
    for (int c = 0; c < 128; c++)
      s += vb_s[c] * Wo[(size_t)(c0 + c) * DIM + e];
    atomicAdd(&obar[b * DIM + e], s);
  } else {
    const int b = bid - 32;
    const int i0 = seg[b * 2];
    const int cnt = min(seg[b * 2 + 1], RMAX);
    for (int r = 0; r < cnt; r++) {
      float* orow = out + (size_t)(b * NTXT + i0 + r) * DIM;
      orow[tid] = 0.f;
      orow[tid + 512] = 0.f;
    }
  }
}

// ---------------------------------------------------------------------------
// K4: blocks 0..4095    : fill (zero / obar / rare direct fallback)
//     blocks 4096..5119 : attn per (b,h,r-stride): q from qpart, scores,
//                         softmax, PV, then partial oproj atomicAdd into out
// ---------------------------------------------------------------------------
__global__ __launch_bounds__(256) void k4_fill_attn(
    const float* __restrict__ text, const _Float16* __restrict__ kv16,
    const float* __restrict__ Wq, const float* __restrict__ Wo,
    const float* __restrict__ gamma, const float* __restrict__ beta,
    const int* __restrict__ tt, const int* __restrict__ seg,
    const float* __restrict__ obar, const float* __restrict__ qpart,
    float* __restrict__ out) {
  __shared__ float red[256];
  __shared__ float pbuf[256];
  const int idx = blockIdx.x;
  const int tid = threadIdx.x;
  if (idx < BATCH * NTXT) {
    const int b = idx >> 11;
    const int i = idx & (NTXT - 1);
    const int t = tt[idx];
    float* orow = out + (size_t)idx * DIM;
    if (t == 0) {
      *reinterpret_cast<float4*>(&orow[tid * 4]) =
          make_float4(0.f, 0.f, 0.f, 0.f);
      return;
    }
    if (t > TMED) {
      *reinterpret_cast<float4*>(&orow[tid * 4]) =
          *reinterpret_cast<const float4*>(&obar[b * DIM + tid * 4]);
      return;
    }
    if (i - seg[b * 2] < RMAX) return;   // handled by attn blocks
    // ---- rare direct fallback (row beyond RMAX) ----
    __shared__ float tns[DIM];
    __shared__ float qrow[DIM];
    __shared__ float oaccs[DIM];
    const float* xrow = text + (size_t)idx * DIM;
    float x[4];
    float s = 0.f;
#pragma unroll
    for (int u = 0; u < 4; u++) { x[u] = xrow[tid + 256 * u]; s += x[u]; }
    red[tid] = s; __syncthreads();
    for (int st = 128; st > 0; st >>= 1) {
      if (tid < st) red[tid] += red[tid + st];
      __syncthreads();
    }
    const float mu = red[0] * (1.0f / DIM); __syncthreads();
    float vs = 0.f;
#pragma unroll
    for (int u = 0; u < 4; u++) { float d = x[u] - mu; vs += d * d; }
    red[tid] = vs; __syncthreads();
    for (int st = 128; st > 0; st >>= 1) {
      if (tid < st) red[tid] += red[tid + st];
      __syncthreads();
    }
    const float rstd = rsqrtf(red[0] * (1.0f / DIM) + 1e-5f); __syncthreads();
#pragma unroll
    for (int u = 0; u < 4; u++) {
      const int c = tid + 256 * u;
      tns[c] = (x[u] - mu) * rstd * gamma[c] + beta[c];
    }
    __syncthreads();
    {
      float qa[4] = {0.f, 0.f, 0.f, 0.f};
      for (int c = 0; c < DIM; c++) {
        const float tv = tns[c];
        const float* wp = Wq + (size_t)c * DIM + tid;
#pragma unroll
        for (int u = 0; u < 4; u++) qa[u] += tv * wp[256 * u];
      }
#pragma unroll
      for (int u = 0; u < 4; u++) qrow[tid + 256 * u] = qa[u];
    }
    __syncthreads();
    const size_t kvrow0 = (size_t)(b * TM + (t - 1) * MMED) * KVW;
    const int d0 = tid & 63, g = tid >> 6;
    for (int h = 0; h < NH; h++) {
      const _Float16* krow = kv16 + kvrow0 + (size_t)tid * KVW + h * DHD;
      float sc = 0.f;
#pragma unroll
      for (int d = 0; d < DHD; d++) sc += qrow[h * DHD + d] * (float)krow[d];
      sc *= 0.125f;
      red[tid] = sc; __syncthreads();
      for (int st = 128; st > 0; st >>= 1) {
        if (tid < st) red[tid] = fmaxf(red[tid], red[tid + st]);
        __syncthreads();
      }
      const float mx = red[0]; __syncthreads();
      const float e = __expf(sc - mx);
      red[tid] = e; __syncthreads();
      for (int st = 128; st > 0; st >>= 1) {
        if (tid < st) red[tid] += red[tid + st];
        __syncthreads();
      }
      const float inv = 1.0f / red[0]; __syncthreads();
      pbuf[tid] = e * inv; __syncthreads();
      const _Float16* vbase =
          kv16 + kvrow0 + (size_t)(g * 64) * KVW + DIM + h * DHD + d0;
      float a = 0.f;
#pragma unroll 8
      for (int jj = 0; jj < 64; jj++)
        a += pbuf[g * 64 + jj] * (float)vbase[(size_t)jj * KVW];
      red[tid] = a; __syncthreads();
      if (tid < 64)
        oaccs[h * DHD + tid] =
            red[tid] + red[64 + tid] + red[128 + tid] + red[192 + tid];
      __syncthreads();
    }
    float oa[4] = {0.f, 0.f, 0.f, 0.f};
    for (int c = 0; c < DIM; c++) {
      const float ov = oaccs[c];
      const float* wp = Wo + (size_t)c * DIM + tid;
#pragma unroll
      for (int u = 0; u < 4; u++) oa[u] += ov * wp[256 * u];
    }
#pragma unroll
    for (int u = 0; u < 4; u++) orow[tid + 256 * u] = oa[u];
  } else {
    // ---- attn + fused partial oproj ----
    __shared__ float qs[DHD];
    __shared__ float oacc_s[DHD];
    const int j = idx - BATCH * NTXT;       // 0..1023
    const int h = j & 15, rt = (j >> 4) & 31, b = j >> 9;
    const int i0 = seg[b * 2];
    const int cnt = min(seg[b * 2 + 1], RMAX);
    const int d0 = tid & 63, g = tid >> 6;
    for (int r = rt; r < cnt; r += 32) {
      const int i = i0 + r;
      const int t = tt[b * NTXT + i];       // in [1, TMED]
      if (tid < 64) {
        const size_t qoff = (size_t)(b * RMAX + r) * DIM + h * DHD + tid;
        qs[tid] = qpart[qoff] + qpart[QSTR + qoff] +
                  qpart[2 * QSTR + qoff] + qpart[3 * QSTR + qoff];
      }
      __syncthreads();
      const size_t kvrow0 = (size_t)(b * TM + (t - 1) * MMED) * KVW;
      const _Float16* krow = kv16 + kvrow0 + (size_t)tid * KVW + h * DHD;
      float sc = 0.f;
#pragma unroll
      for (int d = 0; d < DHD; d += 8) {
        const f16x8 kk = *reinterpret_cast<const f16x8*>(krow + d);
#pragma unroll
        for (int u = 0; u < 8; u++) sc += qs[d + u] * (float)kk[u];
      }
      sc *= 0.125f;
      red[tid] = sc; __syncthreads();
      for (int st = 128; st > 0; st >>= 1) {
        if (tid < st) red[tid] = fmaxf(red[tid], red[tid + st]);
        __syncthreads();
      }
      const float mx = red[0]; __syncthreads();
      const float e = __expf(sc - mx);
      red[tid] = e; __syncthreads();
      for (int st = 128; st > 0; st >>= 1) {
        if (tid < st) red[tid] += red[tid + st];
        __syncthreads();
      }
      const float inv = 1.0f / red[0]; __syncthreads();
      pbuf[tid] = e * inv; __syncthreads();
      const _Float16* vbase =
          kv16 + kvrow0 + (size_t)(g * 64) * KVW + DIM + h * DHD + d0;
      float a = 0.f;
#pragma unroll 8
      for (int jj = 0; jj < 64; jj++)
        a += pbuf[g * 64 + jj] * (float)vbase[(size_t)jj * KVW];
      red[tid] = a; __syncthreads();
      if (tid < 64)
        oacc_s[tid] = red[tid] + red[64 + tid] + red[128 + tid] + red[192 + tid];
      __syncthreads();
      // partial oproj: out[i, e] += sum_d oacc_s[d] * Wo[h*64+d, e]
      float* orow = out + (size_t)(b * NTXT + i) * DIM;
#pragma unroll
      for (int u = 0; u < 4; u++) {
        const int e2 = tid + 256 * u;
        float s2 = 0.f;
#pragma unroll 8
        for (int d = 0; d < DHD; d++)
          s2 += oacc_s[d] * Wo[(size_t)(h * DHD + d) * DIM + e2];
        atomicAdd(&orow[e2], s2);
      }
      __syncthreads();
    }
  }
}

// ---------------------------------------------------------------------------
extern "C" void kernel_launch(void* const* d_in, const int* in_sizes, int n_in,
                              void* d_out, int out_size, void* d_ws, size_t ws_size,
                              hipStream_t stream) {
  const float* text  = (const float*)d_in[0];
  const float* image = (const float*)d_in[1];
  const int*   loc   = (const int*)d_in[2];
  const float* Wq    = (const float*)d_in[3];
  const float* Wkv   = (const float*)d_in[4];
  const float* Wo    = (const float*)d_in[5];
  const float* gamma = (const float*)d_in[6];
  const float* beta  = (const float*)d_in[7];
  float* out = (float*)d_out;

  // ws layout: kv16 8MB | WkvT 4MB | qpart 4x2MB | vbar | obar | tt | seg
  _Float16* kv16  = (_Float16*)d_ws;
  _Float16* WkvT  = kv16 + (size_t)BATCH * TM * KVW;
  float*    qpart = (float*)(WkvT + (size_t)KVW * DIM);
  float*    vbar  = qpart + 4 * QSTR;
  float*    obar  = vbar + BATCH * DIM;
  int*      tt    = (int*)(obar + BATCH * DIM);
  int*      seg   = tt + BATCH * NTXT;

  k1_prep<<<515, 256, 0, stream>>>(loc, Wkv, tt, seg, vbar, WkvT);
  k2_gemm_qproj<<<320, 512, 0, stream>>>(image, WkvT, text, Wq, gamma, beta,
                                         seg, kv16, qpart, vbar);
  k3_obar_zero<<<34, 512, 0, stream>>>(vbar, Wo, seg, obar, out);
  k4_fill_attn<<<BATCH * NTXT + NH * 32 * BATCH, 256, 0, stream>>>(
      text, kv16, Wq, Wo, gamma, beta, tt, seg, obar, qpart, out);
}